// Round 7
// baseline (98.842 us; speedup 1.0000x reference)
//
#include <hip/hip_runtime.h>

#define T_LEN     2000000
#define NT        5
#define START_TAG 3
#define STOP_TAG  4
#define CH        8              // time steps per thread
#define BTHR      256
#define NBLK      1024           // 1024*256*8 = 2,097,152 >= 2e6
#define SPB       (BTHR * CH)    // 2048 steps per block
#define GOFF      (NBLK * 13)    // float index of gold partials in ws (layout: ws[k*NBLK+b])
#define ID_OFF    (-1.0e30f)     // sentinel: identity element

// Reduced scaled transfer matrix: rows {0,1,2} x cols {0,1,2,START}, slot 12 =
// log offset. Rows START/STOP and col STOP are semiring-zero (exp(NEG)=0) and
// contribute nothing to alpha, so they are dropped. off < -1e29 = identity.
__device__ __forceinline__ void compose13(const float* L, const float* R, float* C) {
    float t[12];
#pragma unroll
    for (int j = 0; j < 3; ++j)
#pragma unroll
        for (int s = 0; s < 4; ++s)
            t[j * 4 + s] = fmaf(L[j * 4 + 0], R[0 * 4 + s],
                           fmaf(L[j * 4 + 1], R[1 * 4 + s],
                                L[j * 4 + 2] * R[2 * 4 + s]));
    float m = t[0];
#pragma unroll
    for (int k = 1; k < 12; ++k) m = fmaxf(m, t[k]);
    const float r    = 1.0f / m;
    const float toff = L[12] + R[12] + __logf(m);
    const bool  Lid  = L[12] < -1e29f;
    const bool  Rid  = R[12] < -1e29f;
#pragma unroll
    for (int k = 0; k < 12; ++k)
        C[k] = Rid ? L[k] : (Lid ? R[k] : t[k] * r);
    C[12] = Rid ? L[12] : (Lid ? R[12] : toff);
}

// 64-lane order-aware butterfly: lane i holds time-segment i (13 floats + gold).
// After 6 levels every lane holds the full in-order product. (verified R4-R6)
__device__ __forceinline__ void wave_tree(float* acc, float& g, int lane) {
#pragma unroll
    for (int d = 1; d < 64; d <<= 1) {
        float P[13], C[13];
#pragma unroll
        for (int k = 0; k < 13; ++k) P[k] = __shfl_xor(acc[k], d, 64);
        const float gp = __shfl_xor(g, d, 64);
        if (lane & d) compose13(acc, P, C);   // mine is the later segment
        else          compose13(P, acc, C);   // partner is later
#pragma unroll
        for (int k = 0; k < 13; ++k) acc[k] = C[k];
        g += gp;
    }
}

__global__ __launch_bounds__(BTHR, 4) void crf_phase1(
    const float* __restrict__ feats, const int* __restrict__ tags,
    const float* __restrict__ trans, float* __restrict__ ws)
{
    // LDS: reduce buffers only (14336 B) + trans (100 B)
    __shared__ float sM[BTHR * 13];
    __shared__ float sG[BTHR];
    __shared__ float sTr[NT * NT];

    const int tid = threadIdx.x;
    if (tid < NT * NT) sTr[tid] = trans[tid];
    __syncthreads();                                 // before any global loads -> no vmcnt drain

    const long start  = (long)blockIdx.x * SPB + (long)tid * CH;
    const bool active = (start < T_LEN);             // active chunks always full (2e6 % 8 == 0)

    float A[12];
    float off  = ID_OFF;
    float gold = 0.0f;

    if (active) {
        // ---- direct per-thread loads: 160 B feats (10x float4) + 32 B tags (2x int4) ----
        __align__(16) float fr[CH * NT];             // stays in VGPRs (all indices constant)
        const float* gF = feats + start * NT;        // byte offset start*20 -> 16B-aligned
#pragma unroll
        for (int k = 0; k < (CH * NT) / 4; ++k)
            *(float4*)(fr + 4 * k) = *(const float4*)(gF + 4 * k);

        int tg[CH];
        {
            const int4 a = *(const int4*)(tags + start);
            const int4 b = *(const int4*)(tags + start + 4);
            tg[0] = a.x; tg[1] = a.y; tg[2] = a.z; tg[3] = a.w;
            tg[4] = b.x; tg[5] = b.y; tg[6] = b.z; tg[7] = b.w;
        }
        // boundary tag: previous thread's last tag via shfl; only lane 0 loads global
        const int lane  = tid & 63;
        const int upTag = __shfl_up(tg[CH - 1], 1, 64);
        int prev;
        if (lane) prev = upTag;
        else      prev = (start == 0) ? START_TAG : tags[start - 1];

        // E[j][s] = exp(trans[j][s]), j in {0,1,2}, s in {0,1,2,START}
        float E[12];
#pragma unroll
        for (int j = 0; j < 3; ++j)
#pragma unroll
            for (int s = 0; s < 4; ++s)
                E[j * 4 + s] = __expf(sTr[j * NT + s]);

        // step 0: A = diag(e) * E   (A_prev = I on live rows/cols)
        {
            const float f0 = fr[0], f1 = fr[1], f2 = fr[2];
            const float e0 = __expf(f0), e1 = __expf(f1), e2 = __expf(f2);
#pragma unroll
            for (int s = 0; s < 4; ++s) {
                A[0 * 4 + s] = e0 * E[0 * 4 + s];
                A[1 * 4 + s] = e1 * E[1 * 4 + s];
                A[2 * 4 + s] = e2 * E[2 * 4 + s];
            }
            const int t0 = tg[0];
            gold = sTr[t0 * NT + prev] + (t0 == 0 ? f0 : (t0 == 1 ? f1 : f2));
            prev = t0;
        }
        // steps 1..7
#pragma unroll
        for (int t = 1; t < CH; ++t) {
            const float f0 = fr[t * NT + 0], f1 = fr[t * NT + 1], f2 = fr[t * NT + 2];
            const float e0 = __expf(f0), e1 = __expf(f1), e2 = __expf(f2);
            float N[12];
#pragma unroll
            for (int s = 0; s < 4; ++s) {
                const float a0 = A[0 * 4 + s], a1 = A[1 * 4 + s], a2 = A[2 * 4 + s];
                N[0 * 4 + s] = e0 * fmaf(E[0], a0, fmaf(E[1], a1, E[2] * a2));
                N[1 * 4 + s] = e1 * fmaf(E[4], a0, fmaf(E[5], a1, E[6] * a2));
                N[2 * 4 + s] = e2 * fmaf(E[8], a0, fmaf(E[9], a1, E[10] * a2));
            }
#pragma unroll
            for (int k = 0; k < 12; ++k) A[k] = N[k];

            const int t1 = tg[t];
            gold += sTr[t1 * NT + prev] + (t1 == 0 ? f0 : (t1 == 1 ? f1 : f2));
            prev = t1;
        }
        // normalize once per chunk (max growth ~e^75 from 1.0 — safe fp32; verified R3)
        float m = A[0];
#pragma unroll
        for (int k = 1; k < 12; ++k) m = fmaxf(m, A[k]);
        const float r = 1.0f / m;
#pragma unroll
        for (int k = 0; k < 12; ++k) A[k] *= r;
        off = __logf(m);

        if (start + CH == T_LEN) gold += sTr[STOP_TAG * NT + prev];
    } else {
#pragma unroll
        for (int k = 0; k < 12; ++k) A[k] = 0.0f;
    }

    // ---- block reduce: LDS store once, 64 lanes compose 4, then shuffle tree ----
#pragma unroll
    for (int k = 0; k < 12; ++k) sM[tid * 13 + k] = A[k];
    sM[tid * 13 + 12] = off;
    sG[tid]           = gold;
    __syncthreads();

    if (tid < 64) {
        float acc[13];
#pragma unroll
        for (int k = 0; k < 13; ++k) acc[k] = sM[(4 * tid) * 13 + k];
        float g = sG[4 * tid];
#pragma unroll
        for (int q = 1; q < 4; ++q) {
            float nxt[13], C[13];
#pragma unroll
            for (int k = 0; k < 13; ++k) nxt[k] = sM[(4 * tid + q) * 13 + k];
            compose13(nxt, acc, C);
#pragma unroll
            for (int k = 0; k < 13; ++k) acc[k] = C[k];
            g += sG[4 * tid + q];
        }
        wave_tree(acc, g, tid);

        // all 64 lanes hold the block result; store TRANSPOSED: ws[k*NBLK + b]
        float v = acc[0];
#pragma unroll
        for (int k = 1; k < 13; ++k) v = (tid == k) ? acc[k] : v;
        if (tid < 13)  ws[tid * NBLK + blockIdx.x] = v;
        if (tid == 13) ws[GOFF + blockIdx.x] = g;
    }
}

__global__ __launch_bounds__(256) void crf_phase2(
    const float* __restrict__ trans, const float* __restrict__ ws,
    float* __restrict__ out)
{
    __shared__ float sM[256 * 13];
    __shared__ float sG[256];

    const int tid = threadIdx.x;

    // hoist ALL loads (coalesced via transposed layout), then compose chain
    {
        float M[4][13];
#pragma unroll
        for (int q = 0; q < 4; ++q)
#pragma unroll
            for (int k = 0; k < 13; ++k)
                M[q][k] = ws[k * NBLK + 4 * tid + q];
        float g = ws[GOFF + 4 * tid] + ws[GOFF + 4 * tid + 1]
                + ws[GOFF + 4 * tid + 2] + ws[GOFF + 4 * tid + 3];

        float acc[13], C[13];
#pragma unroll
        for (int k = 0; k < 13; ++k) acc[k] = M[0][k];
#pragma unroll
        for (int q = 1; q < 4; ++q) {
            compose13(M[q], acc, C);
#pragma unroll
            for (int k = 0; k < 13; ++k) acc[k] = C[k];
        }
#pragma unroll
        for (int k = 0; k < 13; ++k) sM[tid * 13 + k] = acc[k];
        sG[tid] = g;
    }
    __syncthreads();

    if (tid < 64) {
        float acc[13];
#pragma unroll
        for (int k = 0; k < 13; ++k) acc[k] = sM[(4 * tid) * 13 + k];
        float g = sG[4 * tid];
#pragma unroll
        for (int q = 1; q < 4; ++q) {
            float nxt[13], C[13];
#pragma unroll
            for (int k = 0; k < 13; ++k) nxt[k] = sM[(4 * tid + q) * 13 + k];
            compose13(nxt, acc, C);
#pragma unroll
            for (int k = 0; k < 13; ++k) acc[k] = C[k];
            g += sG[4 * tid + q];
        }
        wave_tree(acc, g, tid);

        if (tid == 0) {
            // alpha = off + log( sum_{j<3} M[j][START] * exp(trans[STOP][j]) )
            float s = 0.0f;
#pragma unroll
            for (int j = 0; j < 3; ++j)
                s += acc[j * 4 + 3] * __expf(trans[STOP_TAG * NT + j]);
            const float alpha = acc[12] + __logf(s);
            out[0] = alpha - g;
        }
    }
}

extern "C" void kernel_launch(void* const* d_in, const int* in_sizes, int n_in,
                              void* d_out, int out_size, void* d_ws, size_t ws_size,
                              hipStream_t stream) {
    const float* feats = (const float*)d_in[0];
    const int*   tags  = (const int*)d_in[1];
    const float* trans = (const float*)d_in[2];
    float*       out   = (float*)d_out;
    float*       ws    = (float*)d_ws;

    crf_phase1<<<NBLK, BTHR, 0, stream>>>(feats, tags, trans, ws);
    crf_phase2<<<1, 256, 0, stream>>>(trans, ws, out);
}